// Round 3
// baseline (327.214 us; speedup 1.0000x reference)
//
#include <hip/hip_runtime.h>
#include <hip/hip_bf16.h>

typedef unsigned short u16t;
typedef __attribute__((ext_vector_type(8))) short short8;
typedef __attribute__((ext_vector_type(4))) unsigned short ushort4v;
typedef __attribute__((ext_vector_type(4))) float f32x4;

__device__ __forceinline__ float bf2f(u16t u) {
  union { unsigned int i; float f; } v; v.i = ((unsigned int)u) << 16; return v.f;
}
__device__ __forceinline__ u16t f2bf(float f) {
  __hip_bfloat16 h = __float2bfloat16(f);
  union { __hip_bfloat16 b; u16t u; } v; v.b = h; return v.u;
}

// Kernel 1: sobel conv (bf16 LDS, fp32 accum) + fc0(relu) + fc1 via bf16 MFMA + stoch mask.
// out = x + dx (no life mask yet). Block tile: 2(z1) x 2(z2) x 64(z3); 256 threads.
__global__ __launch_bounds__(256, 2) void nca_main(
    const float* __restrict__ xg, const float* __restrict__ w0g,
    const float* __restrict__ b0g, const float* __restrict__ w1g,
    const float* __restrict__ stg, float* __restrict__ outg)
{
  __shared__ u16t xs[8704];    // [4][4][34][16] bf16 x halo (2 z3 passes); reused as h buffers
  __shared__ u16t ys[16384];   // [8 kchunks][256 voxels][8] bf16 y, MFMA-A-friendly
  __shared__ float st_l[256];  // stoch fp32

  const int t = threadIdx.x;
  const int bid = blockIdx.x;
  const int b = bid >> 10;
  const int z1base = ((bid >> 5) & 31) * 2;
  const int z2base = (bid & 31) * 2;

  {
    int z1 = t >> 7, z2 = (t >> 6) & 1, z3 = t & 63;
    int gv = ((b * 64 + z1base + z1) * 64 + (z2base + z2)) * 64 + z3;
    st_l[t] = stg[gv];
  }

  for (int p = 0; p < 2; ++p) {
    if (p) __syncthreads();  // xs WAR vs previous pass conv reads
    // stage x halo (fp32 -> bf16): 544 rows x 16 ch = 2176 float4 chunks
    for (int it = 0; it < 9; ++it) {
      int q = t + it * 256;
      if (q < 2176) {
        int c4 = (q & 3) * 4, s = q >> 2;
        int i3 = s % 34, r = s / 34;
        int i2 = r & 3, i1 = r >> 2;
        int z1g = z1base + i1 - 1, z2g = z2base + i2 - 1, z3g = p * 32 + i3 - 1;
        f32x4 val = {0.f, 0.f, 0.f, 0.f};
        if ((unsigned)z1g < 64u && (unsigned)z2g < 64u && (unsigned)z3g < 64u) {
          int gv = ((b * 64 + z1g) * 64 + z2g) * 64 + z3g;
          val = *(const f32x4*)(xg + gv * 16 + c4);
        }
        ushort4v bv;
        #pragma unroll
        for (int j = 0; j < 4; ++j) bv[j] = f2bf(val[j]);
        *(ushort4v*)(xs + s * 16 + c4) = bv;
      }
    }
    __syncthreads();
    // conv: one (voxel, channel-half) per thread
    {
      const int hc = t & 1, v128 = t >> 1;
      const int z1 = v128 >> 6, z2 = (v128 >> 5) & 1, z3l = v128 & 31;
      const int v = z1 * 128 + z2 * 64 + p * 32 + z3l;
      float ax[8], ay[8], az[8];
      #pragma unroll
      for (int c = 0; c < 8; ++c) { ax[c] = 0.f; ay[c] = 0.f; az[c] = 0.f; }
      typedef __attribute__((ext_vector_type(8))) unsigned short ushort8;
      ushort8 ctr{};
      const float W[3] = {1.f, 2.f, 1.f};
      const float D[3] = {-1.f, 0.f, 1.f};
      #pragma unroll
      for (int d1 = 0; d1 < 3; ++d1)
        #pragma unroll
        for (int d2 = 0; d2 < 3; ++d2)
          #pragma unroll
          for (int d3 = 0; d3 < 3; ++d3) {
            const int base = (((z1 + d1) * 4 + (z2 + d2)) * 34 + (z3l + d3)) * 16 + hc * 8;
            ushort8 u = *(const ushort8*)(xs + base);
            float f[8];
            #pragma unroll
            for (int c = 0; c < 8; ++c) f[c] = bf2f((u16t)u[c]);
            const float cx = W[d1] * W[d2] * D[d3] * 0.03125f;  // kx[k,i,j]=w[k]w[i]d[j]/32
            const float cy = W[d1] * D[d2] * W[d3] * 0.03125f;  // ky=kx.T(0,2,1)
            const float cz = D[d1] * W[d2] * W[d3] * 0.03125f;  // kz=kx.T(2,1,0)
            if (cx != 0.f) {
              #pragma unroll
              for (int c = 0; c < 8; ++c) ax[c] = fmaf(f[c], cx, ax[c]);
            }
            if (cy != 0.f) {
              #pragma unroll
              for (int c = 0; c < 8; ++c) ay[c] = fmaf(f[c], cy, ay[c]);
            }
            if (cz != 0.f) {
              #pragma unroll
              for (int c = 0; c < 8; ++c) az[c] = fmaf(f[c], cz, az[c]);
            }
            if (d1 == 1 && d2 == 1 && d3 == 1) ctr = u;
          }
      *(ushort8*)(ys + (0 + hc) * 2048 + v * 8) = ctr;
      ushort8 bx, by, bz;
      #pragma unroll
      for (int c = 0; c < 8; ++c) {
        bx[c] = (short)f2bf(ax[c]); by[c] = (short)f2bf(ay[c]); bz[c] = (short)f2bf(az[c]);
      }
      *(ushort8*)(ys + (2 + hc) * 2048 + v * 8) = bx;
      *(ushort8*)(ys + (4 + hc) * 2048 + v * 8) = by;
      *(ushort8*)(ys + (6 + hc) * 2048 + v * 8) = bz;
    }
  }
  __syncthreads();

  // GEMM phase: per wave M=64 (4 m-tiles of 16); fc0 K=64 N=128; fc1 K=128 N=16
  {
    const int lane = t & 63, w = t >> 6;
    const int col = lane & 15, quad = lane >> 4;
    short8 w0f[2][8];  // B[k=kt*32+quad*8+j][n=nt*16+col] = w0[n][k], cvt fp32->bf16
    #pragma unroll
    for (int kt = 0; kt < 2; ++kt)
      #pragma unroll
      for (int nt = 0; nt < 8; ++nt) {
        const float* p = w0g + (nt * 16 + col) * 64 + kt * 32 + quad * 8;
        f32x4 lo = *(const f32x4*)p, hi = *(const f32x4*)(p + 4);
        short8 fr;
        #pragma unroll
        for (int j = 0; j < 4; ++j) { fr[j] = (short)f2bf(lo[j]); fr[4 + j] = (short)f2bf(hi[j]); }
        w0f[kt][nt] = fr;
      }
    short8 w1f[4];     // B[k][n=col] = w1[col][k]
    #pragma unroll
    for (int kt = 0; kt < 4; ++kt) {
      const float* p = w1g + col * 128 + kt * 32 + quad * 8;
      f32x4 lo = *(const f32x4*)p, hi = *(const f32x4*)(p + 4);
      short8 fr;
      #pragma unroll
      for (int j = 0; j < 4; ++j) { fr[j] = (short)f2bf(lo[j]); fr[4 + j] = (short)f2bf(hi[j]); }
      w1f[kt] = fr;
    }
    float bias[8];
    #pragma unroll
    for (int nt = 0; nt < 8; ++nt) bias[nt] = b0g[nt * 16 + col];

    u16t* hw = xs + w * 2176;  // per-wave h buffer [16][136]

    for (int mt = 0; mt < 4; ++mt) {
      const int mbase = w * 64 + mt * 16;
      short8 aF[2];  // A[m=col][k=kt*32+quad*8+j] = y[mbase+col][k]
      #pragma unroll
      for (int kt = 0; kt < 2; ++kt)
        aF[kt] = *(const short8*)(ys + (kt * 4 + quad) * 2048 + (mbase + col) * 8);
      f32x4 acc[8];
      #pragma unroll
      for (int nt = 0; nt < 8; ++nt) {
        f32x4 tmp = {bias[nt], bias[nt], bias[nt], bias[nt]};
        acc[nt] = tmp;
      }
      #pragma unroll
      for (int kt = 0; kt < 2; ++kt)
        #pragma unroll
        for (int nt = 0; nt < 8; ++nt)
          acc[nt] = __builtin_amdgcn_mfma_f32_16x16x32_bf16(aF[kt], w0f[kt][nt], acc[nt], 0, 0, 0);
      // relu -> bf16 -> LDS (C layout -> A layout); h[m=quad*4+r][k=nt*16+col]
      #pragma unroll
      for (int nt = 0; nt < 8; ++nt)
        #pragma unroll
        for (int r = 0; r < 4; ++r)
          hw[(quad * 4 + r) * 136 + nt * 16 + col] = f2bf(fmaxf(acc[nt][r], 0.0f));
      __syncthreads();  // order LDS write -> vector read (uniform loop, legal)
      f32x4 dxa = {0.f, 0.f, 0.f, 0.f};
      #pragma unroll
      for (int kt = 0; kt < 4; ++kt) {
        short8 ah = *(const short8*)(hw + col * 136 + kt * 32 + quad * 8);
        dxa = __builtin_amdgcn_mfma_f32_16x16x32_bf16(ah, w1f[kt], dxa, 0, 0, 0);
      }
      // epilogue: out[v][col] = x[v][col] + mask*dx ; v = mbase+quad*4+r
      #pragma unroll
      for (int r = 0; r < 4; ++r) {
        const int v = mbase + quad * 4 + r;
        const int gv = ((b * 64 + z1base + (v >> 7)) * 64 + (z2base + ((v >> 6) & 1))) * 64 + (v & 63);
        const int addr = gv * 16 + col;
        float dx = (st_l[v] > 0.5f) ? dxa[r] : 0.0f;
        outg[addr] = xg[addr] + dx;
      }
    }
  }
}

// Kernel 2: life = (maxpool3(alpha(x)) > 0.1) & (maxpool3(alpha(x2)) > 0.1); zero dead voxels.
// Reads alpha(x) from xg and alpha(x2) from outg directly — no workspace.
__global__ void nca_life(const float* __restrict__ xg, const float* __restrict__ outg,
                         float* __restrict__ og)
{
  __shared__ float a2x[1056];  // [4][4][66] alpha(x)
  __shared__ float a2o[1056];  // [4][4][66] alpha(x2)
  const int t = threadIdx.x, bid = blockIdx.x;
  const int b = bid >> 10;
  const int z1base = ((bid >> 5) & 31) * 2;
  const int z2base = (bid & 31) * 2;
  for (int it = 0; it < 5; ++it) {
    int q = t + it * 256;
    if (q < 1056) {
      int i3 = q % 66, r = q / 66;
      int i2 = r & 3, i1 = r >> 2;
      int z1g = z1base + i1 - 1, z2g = z2base + i2 - 1, z3g = i3 - 1;
      float vx = 0.f, vo = 0.f;  // 0 pad: same >0.1 verdict as -inf pad
      if ((unsigned)z1g < 64u && (unsigned)z2g < 64u && (unsigned)z3g < 64u) {
        int gv = ((b * 64 + z1g) * 64 + z2g) * 64 + z3g;
        vx = xg[gv * 16 + 3];
        vo = outg[gv * 16 + 3];
      }
      a2x[q] = vx; a2o[q] = vo;
    }
  }
  __syncthreads();
  const int z1 = t >> 7, z2 = (t >> 6) & 1, z3 = t & 63;
  float mx = -1e30f, mo = -1e30f;
  #pragma unroll
  for (int d1 = 0; d1 < 3; ++d1)
    #pragma unroll
    for (int d2 = 0; d2 < 3; ++d2)
      #pragma unroll
      for (int d3 = 0; d3 < 3; ++d3) {
        const int idx = ((z1 + d1) * 4 + (z2 + d2)) * 66 + (z3 + d3);
        mx = fmaxf(mx, a2x[idx]);
        mo = fmaxf(mo, a2o[idx]);
      }
  const bool life = (mx > 0.1f) && (mo > 0.1f);
  if (!life) {
    const int gv = ((b * 64 + z1base + z1) * 64 + (z2base + z2)) * 64 + z3;
    f32x4 z = {0.f, 0.f, 0.f, 0.f};
    #pragma unroll
    for (int j = 0; j < 4; ++j) *(f32x4*)(og + gv * 16 + j * 4) = z;
  }
}

extern "C" void kernel_launch(void* const* d_in, const int* in_sizes, int n_in,
                              void* d_out, int out_size, void* d_ws, size_t ws_size,
                              hipStream_t stream) {
  (void)out_size; (void)d_ws; (void)ws_size;
  // Identify inputs by (unique) element counts; fall back to positional order.
  const void *px = nullptr, *pw0 = nullptr, *pb0 = nullptr, *pw1 = nullptr, *pst = nullptr;
  for (int i = 0; i < n_in; ++i) {
    switch (in_sizes[i]) {
      case 16777216: px  = d_in[i]; break;  // x  [4,64,64,64,16]
      case 8192:     pw0 = d_in[i]; break;  // w0 [128,64]
      case 128:      pb0 = d_in[i]; break;  // b0 [128]
      case 2048:     pw1 = d_in[i]; break;  // w1 [16,128]
      case 1048576:  pst = d_in[i]; break;  // stoch [4,64,64,64,1]
    }
  }
  if (!px || !pw0 || !pb0 || !pw1 || !pst) {
    px = d_in[0]; pw0 = d_in[1]; pb0 = d_in[2]; pw1 = d_in[3]; pst = d_in[4];
  }
  float* outg = (float*)d_out;
  nca_main<<<4096, 256, 0, stream>>>((const float*)px, (const float*)pw0, (const float*)pb0,
                                     (const float*)pw1, (const float*)pst, outg);
  nca_life<<<4096, 256, 0, stream>>>((const float*)px, outg, outg);
}

// Round 4
// 327.096 us; speedup vs baseline: 1.0004x; 1.0004x over previous
//
#include <hip/hip_runtime.h>
#include <hip/hip_bf16.h>

typedef unsigned short u16t;
typedef __attribute__((ext_vector_type(8))) short short8;
typedef __attribute__((ext_vector_type(8))) unsigned short ushort8;
typedef __attribute__((ext_vector_type(4))) unsigned short ushort4v;
typedef __attribute__((ext_vector_type(4))) float f32x4;

#define VTOT 1048576

__device__ __forceinline__ float bf2f(u16t u) {
  union { unsigned int i; float f; } v; v.i = ((unsigned int)u) << 16; return v.f;
}
__device__ __forceinline__ u16t f2bf(float f) {
  __hip_bfloat16 h = __float2bfloat16(f);
  union { __hip_bfloat16 b; u16t u; } v; v.b = h; return v.u;
}

// Kernel 1: sobel conv (bf16 LDS, fp32 accum) + fc0(relu) + fc1 via bf16 MFMA + stoch mask.
// out = x + dx. Also: plife (maxpool3 alpha(x) > 0.1) and aws = fp32 alpha(x2).
// Block tile: 2(z1) x 2(z2) x 64(z3); 256 threads = 4 waves.
__global__ __launch_bounds__(256, 3) void nca_main(
    const float* __restrict__ xg, const float* __restrict__ w0g,
    const float* __restrict__ b0g, const float* __restrict__ w1g,
    const float* __restrict__ stg, float* __restrict__ outg,
    float* __restrict__ aws, unsigned char* __restrict__ plife)
{
  __shared__ u16t xs[8704];    // [4][4][34][16] bf16 x halo (2 z3 passes); reused as h buffers
  __shared__ u16t ys[16384];   // [8 kchunks][256 voxels][8] bf16 y, MFMA-A-friendly
  __shared__ float st_l[256];  // stoch fp32

  const int t = threadIdx.x;
  const int bid = blockIdx.x;
  const int b = bid >> 10;
  const int z1base = ((bid >> 5) & 31) * 2;
  const int z2base = (bid & 31) * 2;

  {
    int z1 = t >> 7, z2 = (t >> 6) & 1, z3 = t & 63;
    int gv = ((b * 64 + z1base + z1) * 64 + (z2base + z2)) * 64 + z3;
    st_l[t] = stg[gv];
  }

  for (int p = 0; p < 2; ++p) {
    if (p) __syncthreads();  // xs WAR vs previous pass conv reads
    // stage x halo (fp32 -> bf16): 544 rows x 16 ch = 2176 float4 chunks
    for (int it = 0; it < 9; ++it) {
      int q = t + it * 256;
      if (q < 2176) {
        int c4 = (q & 3) * 4, s = q >> 2;
        int i3 = s % 34, r = s / 34;
        int i2 = r & 3, i1 = r >> 2;
        int z1g = z1base + i1 - 1, z2g = z2base + i2 - 1, z3g = p * 32 + i3 - 1;
        f32x4 val = {0.f, 0.f, 0.f, 0.f};
        if ((unsigned)z1g < 64u && (unsigned)z2g < 64u && (unsigned)z3g < 64u) {
          int gv = ((b * 64 + z1g) * 64 + z2g) * 64 + z3g;
          val = *(const f32x4*)(xg + gv * 16 + c4);
        }
        ushort4v bv;
        #pragma unroll
        for (int j = 0; j < 4; ++j) bv[j] = f2bf(val[j]);
        *(ushort4v*)(xs + s * 16 + c4) = bv;
      }
    }
    __syncthreads();
    // conv: one (voxel, channel-half) per thread
    {
      const int hc = t & 1, v128 = t >> 1;
      const int z1 = v128 >> 6, z2 = (v128 >> 5) & 1, z3l = v128 & 31;
      const int v = z1 * 128 + z2 * 64 + p * 32 + z3l;
      float ax[8], ay[8], az[8];
      #pragma unroll
      for (int c = 0; c < 8; ++c) { ax[c] = 0.f; ay[c] = 0.f; az[c] = 0.f; }
      ushort8 ctr{};
      float amax = 0.0f;  // alpha>=0; 0-pad gives same >0.1 verdict as -inf pad
      const float W[3] = {1.f, 2.f, 1.f};
      const float D[3] = {-1.f, 0.f, 1.f};
      #pragma unroll
      for (int d1 = 0; d1 < 3; ++d1)
        #pragma unroll
        for (int d2 = 0; d2 < 3; ++d2)
          #pragma unroll
          for (int d3 = 0; d3 < 3; ++d3) {
            const int base = (((z1 + d1) * 4 + (z2 + d2)) * 34 + (z3l + d3)) * 16 + hc * 8;
            ushort8 u = *(const ushort8*)(xs + base);
            float f[8];
            #pragma unroll
            for (int c = 0; c < 8; ++c) f[c] = bf2f((u16t)u[c]);
            const float cx = W[d1] * W[d2] * D[d3] * 0.03125f;  // kx[k,i,j]=w[k]w[i]d[j]/32
            const float cy = W[d1] * D[d2] * W[d3] * 0.03125f;  // ky=kx.T(0,2,1)
            const float cz = D[d1] * W[d2] * W[d3] * 0.03125f;  // kz=kx.T(2,1,0)
            if (cx != 0.f) {
              #pragma unroll
              for (int c = 0; c < 8; ++c) ax[c] = fmaf(f[c], cx, ax[c]);
            }
            if (cy != 0.f) {
              #pragma unroll
              for (int c = 0; c < 8; ++c) ay[c] = fmaf(f[c], cy, ay[c]);
            }
            if (cz != 0.f) {
              #pragma unroll
              for (int c = 0; c < 8; ++c) az[c] = fmaf(f[c], cz, az[c]);
            }
            if (d1 == 1 && d2 == 1 && d3 == 1) ctr = u;
            amax = fmaxf(amax, f[3]);  // alpha = ch3 (meaningful for hc==0)
          }
      *(ushort8*)(ys + (0 + hc) * 2048 + v * 8) = ctr;
      ushort8 bx, by, bz;
      #pragma unroll
      for (int c = 0; c < 8; ++c) {
        bx[c] = (short)f2bf(ax[c]); by[c] = (short)f2bf(ay[c]); bz[c] = (short)f2bf(az[c]);
      }
      *(ushort8*)(ys + (2 + hc) * 2048 + v * 8) = bx;
      *(ushort8*)(ys + (4 + hc) * 2048 + v * 8) = by;
      *(ushort8*)(ys + (6 + hc) * 2048 + v * 8) = bz;
      if (hc == 0) {
        int gv = ((b * 64 + z1base + (v >> 7)) * 64 + (z2base + ((v >> 6) & 1))) * 64 + (v & 63);
        plife[gv] = (amax > 0.1f) ? (unsigned char)1 : (unsigned char)0;
      }
    }
  }
  __syncthreads();

  // GEMM phase: per wave M=64 (4 m-tiles of 16); fc0 K=64 N=128; fc1 K=128 N=16
  {
    const int lane = t & 63, w = t >> 6;
    const int col = lane & 15, quad = lane >> 4;
    short8 w0f[2][8];  // B[k=kt*32+quad*8+j][n=nt*16+col] = w0[n][k], cvt fp32->bf16
    #pragma unroll
    for (int kt = 0; kt < 2; ++kt)
      #pragma unroll
      for (int nt = 0; nt < 8; ++nt) {
        const float* p = w0g + (nt * 16 + col) * 64 + kt * 32 + quad * 8;
        f32x4 lo = *(const f32x4*)p, hi = *(const f32x4*)(p + 4);
        short8 fr;
        #pragma unroll
        for (int j = 0; j < 4; ++j) { fr[j] = (short)f2bf(lo[j]); fr[4 + j] = (short)f2bf(hi[j]); }
        w0f[kt][nt] = fr;
      }
    short8 w1f[4];     // B[k][n=col] = w1[col][k]
    #pragma unroll
    for (int kt = 0; kt < 4; ++kt) {
      const float* p = w1g + col * 128 + kt * 32 + quad * 8;
      f32x4 lo = *(const f32x4*)p, hi = *(const f32x4*)(p + 4);
      short8 fr;
      #pragma unroll
      for (int j = 0; j < 4; ++j) { fr[j] = (short)f2bf(lo[j]); fr[4 + j] = (short)f2bf(hi[j]); }
      w1f[kt] = fr;
    }
    float bias[8];
    #pragma unroll
    for (int nt = 0; nt < 8; ++nt) bias[nt] = b0g[nt * 16 + col];

    u16t* hw = xs + w * 2176;  // per-wave h buffer [16][136]

    for (int mt = 0; mt < 4; ++mt) {
      const int mbase = w * 64 + mt * 16;
      short8 aF[2];  // A[m=col][k=kt*32+quad*8+j] = y[mbase+col][k]
      #pragma unroll
      for (int kt = 0; kt < 2; ++kt)
        aF[kt] = *(const short8*)(ys + (kt * 4 + quad) * 2048 + (mbase + col) * 8);
      f32x4 acc[8];
      #pragma unroll
      for (int nt = 0; nt < 8; ++nt) {
        f32x4 tmp = {bias[nt], bias[nt], bias[nt], bias[nt]};
        acc[nt] = tmp;
      }
      #pragma unroll
      for (int kt = 0; kt < 2; ++kt)
        #pragma unroll
        for (int nt = 0; nt < 8; ++nt)
          acc[nt] = __builtin_amdgcn_mfma_f32_16x16x32_bf16(aF[kt], w0f[kt][nt], acc[nt], 0, 0, 0);
      // relu -> bf16 -> LDS (C layout -> A layout); h[m=quad*4+r][k=nt*16+col]
      #pragma unroll
      for (int nt = 0; nt < 8; ++nt)
        #pragma unroll
        for (int r = 0; r < 4; ++r)
          hw[(quad * 4 + r) * 136 + nt * 16 + col] = f2bf(fmaxf(acc[nt][r], 0.0f));
      // hw is wave-private; DS ops complete in-order per wave — fence (not barrier) suffices
      __threadfence_block();
      f32x4 dxa = {0.f, 0.f, 0.f, 0.f};
      #pragma unroll
      for (int kt = 0; kt < 4; ++kt) {
        short8 ah = *(const short8*)(hw + col * 136 + kt * 32 + quad * 8);
        dxa = __builtin_amdgcn_mfma_f32_16x16x32_bf16(ah, w1f[kt], dxa, 0, 0, 0);
      }
      __threadfence_block();  // WAR: next mt rewrites hw
      // epilogue: out[v][col] = x[v][col] + mask*dx ; v = mbase+quad*4+r
      #pragma unroll
      for (int r = 0; r < 4; ++r) {
        const int v = mbase + quad * 4 + r;
        const int gv = ((b * 64 + z1base + (v >> 7)) * 64 + (z2base + ((v >> 6) & 1))) * 64 + (v & 63);
        const int addr = gv * 16 + col;
        float dx = (st_l[v] > 0.5f) ? dxa[r] : 0.0f;
        float x2 = xg[addr] + dx;
        outg[addr] = x2;
        if (col == 3) aws[gv] = x2;  // fp32 alpha(x2), pre-mask
      }
    }
  }
}

// Kernel 2 (compact): life = plife & (maxpool3(aws) > 0.1); zero dead voxels in out.
__global__ void nca_life(const float* __restrict__ aws,
                         const unsigned char* __restrict__ plife,
                         float* __restrict__ og)
{
  __shared__ float a2[1056];  // [4][4][66] alpha(x2)
  const int t = threadIdx.x, bid = blockIdx.x;
  const int b = bid >> 10;
  const int z1base = ((bid >> 5) & 31) * 2;
  const int z2base = (bid & 31) * 2;
  for (int it = 0; it < 5; ++it) {
    int q = t + it * 256;
    if (q < 1056) {
      int i3 = q % 66, r = q / 66;
      int i2 = r & 3, i1 = r >> 2;
      int z1g = z1base + i1 - 1, z2g = z2base + i2 - 1, z3g = i3 - 1;
      float vo = 0.f;  // 0 pad: same >0.1 verdict as -inf pad (alpha(x2) can be <0 but 0>0.1 false either way)
      if ((unsigned)z1g < 64u && (unsigned)z2g < 64u && (unsigned)z3g < 64u)
        vo = aws[((b * 64 + z1g) * 64 + z2g) * 64 + z3g];
      a2[q] = vo;
    }
  }
  __syncthreads();
  const int z1 = t >> 7, z2 = (t >> 6) & 1, z3 = t & 63;
  float mo = -1e30f;
  #pragma unroll
  for (int d1 = 0; d1 < 3; ++d1)
    #pragma unroll
    for (int d2 = 0; d2 < 3; ++d2)
      #pragma unroll
      for (int d3 = 0; d3 < 3; ++d3)
        mo = fmaxf(mo, a2[((z1 + d1) * 4 + (z2 + d2)) * 66 + (z3 + d3)]);
  const int gv = ((b * 64 + z1base + z1) * 64 + (z2base + z2)) * 64 + z3;
  const bool life = (plife[gv] != 0) && (mo > 0.1f);
  if (!life) {
    f32x4 z = {0.f, 0.f, 0.f, 0.f};
    #pragma unroll
    for (int j = 0; j < 4; ++j) *(f32x4*)(og + gv * 16 + j * 4) = z;
  }
}

// Fallback (no workspace): recompute both alive masks from strided global reads.
__global__ void nca_life_strided(const float* __restrict__ xg, const float* __restrict__ outg,
                                 float* __restrict__ og)
{
  __shared__ float a2x[1056];
  __shared__ float a2o[1056];
  const int t = threadIdx.x, bid = blockIdx.x;
  const int b = bid >> 10;
  const int z1base = ((bid >> 5) & 31) * 2;
  const int z2base = (bid & 31) * 2;
  for (int it = 0; it < 5; ++it) {
    int q = t + it * 256;
    if (q < 1056) {
      int i3 = q % 66, r = q / 66;
      int i2 = r & 3, i1 = r >> 2;
      int z1g = z1base + i1 - 1, z2g = z2base + i2 - 1, z3g = i3 - 1;
      float vx = 0.f, vo = 0.f;
      if ((unsigned)z1g < 64u && (unsigned)z2g < 64u && (unsigned)z3g < 64u) {
        int gv = ((b * 64 + z1g) * 64 + z2g) * 64 + z3g;
        vx = xg[gv * 16 + 3];
        vo = outg[gv * 16 + 3];
      }
      a2x[q] = vx; a2o[q] = vo;
    }
  }
  __syncthreads();
  const int z1 = t >> 7, z2 = (t >> 6) & 1, z3 = t & 63;
  float mx = -1e30f, mo = -1e30f;
  #pragma unroll
  for (int d1 = 0; d1 < 3; ++d1)
    #pragma unroll
    for (int d2 = 0; d2 < 3; ++d2)
      #pragma unroll
      for (int d3 = 0; d3 < 3; ++d3) {
        const int idx = ((z1 + d1) * 4 + (z2 + d2)) * 66 + (z3 + d3);
        mx = fmaxf(mx, a2x[idx]);
        mo = fmaxf(mo, a2o[idx]);
      }
  const bool life = (mx > 0.1f) && (mo > 0.1f);
  if (!life) {
    const int gv = ((b * 64 + z1base + z1) * 64 + (z2base + z2)) * 64 + z3;
    f32x4 z = {0.f, 0.f, 0.f, 0.f};
    #pragma unroll
    for (int j = 0; j < 4; ++j) *(f32x4*)(og + gv * 16 + j * 4) = z;
  }
}

extern "C" void kernel_launch(void* const* d_in, const int* in_sizes, int n_in,
                              void* d_out, int out_size, void* d_ws, size_t ws_size,
                              hipStream_t stream) {
  (void)out_size;
  const void *px = nullptr, *pw0 = nullptr, *pb0 = nullptr, *pw1 = nullptr, *pst = nullptr;
  for (int i = 0; i < n_in; ++i) {
    switch (in_sizes[i]) {
      case 16777216: px  = d_in[i]; break;  // x  [4,64,64,64,16]
      case 8192:     pw0 = d_in[i]; break;  // w0 [128,64]
      case 128:      pb0 = d_in[i]; break;  // b0 [128]
      case 2048:     pw1 = d_in[i]; break;  // w1 [16,128]
      case 1048576:  pst = d_in[i]; break;  // stoch [4,64,64,64,1]
    }
  }
  if (!px || !pw0 || !pb0 || !pw1 || !pst) {
    px = d_in[0]; pw0 = d_in[1]; pb0 = d_in[2]; pw1 = d_in[3]; pst = d_in[4];
  }
  float* outg = (float*)d_out;
  const size_t need = (size_t)VTOT * 4 + (size_t)VTOT;  // fp32 alpha + byte plife
  const bool use_ws = (d_ws != nullptr) && (ws_size >= need);
  float* aws = use_ws ? (float*)d_ws : outg;  // dummy target if no ws (writes harmless? no—must be valid)
  unsigned char* plife = use_ws ? ((unsigned char*)d_ws + (size_t)VTOT * 4) : nullptr;

  if (use_ws) {
    nca_main<<<4096, 256, 0, stream>>>((const float*)px, (const float*)pw0, (const float*)pb0,
                                       (const float*)pw1, (const float*)pst, outg, aws, plife);
    nca_life<<<4096, 256, 0, stream>>>(aws, plife, outg);
  } else {
    // No usable workspace: write aux into out's tail? Not possible — use strided fallback.
    // Here aws/plife writes must be suppressed; reuse outg-based kernel pair.
    static float* dummy = nullptr;  // never used: fallback kernel ignores aux
    (void)dummy;
    nca_main<<<4096, 256, 0, stream>>>((const float*)px, (const float*)pw0, (const float*)pb0,
                                       (const float*)pw1, (const float*)pst, outg,
                                       (float*)d_out, (unsigned char*)d_out);  // aws/plife aliased to out: values overwritten below
    nca_life_strided<<<4096, 256, 0, stream>>>((const float*)px, outg, outg);
  }
}

// Round 5
// 292.795 us; speedup vs baseline: 1.1176x; 1.1171x over previous
//
#include <hip/hip_runtime.h>
#include <hip/hip_bf16.h>

typedef unsigned short u16t;
typedef __attribute__((ext_vector_type(8))) short short8;
typedef __attribute__((ext_vector_type(8))) unsigned short ushort8;
typedef __attribute__((ext_vector_type(4))) unsigned short ushort4v;
typedef __attribute__((ext_vector_type(4))) float f32x4;

#define VTOT 1048576

__device__ __forceinline__ float bf2f(u16t u) {
  union { unsigned int i; float f; } v; v.i = ((unsigned int)u) << 16; return v.f;
}
__device__ __forceinline__ u16t f2bf(float f) {
  __hip_bfloat16 h = __float2bfloat16(f);
  union { __hip_bfloat16 b; u16t u; } v; v.b = h; return v.u;
}

// Kernel 1: sobel conv (bf16 LDS, fp32 accum) + fc0(relu) + fc1 via bf16 MFMA + stoch mask.
// out = x + dx. Aux (coalesced flush at end): plife = (maxpool3 alpha(x) > 0.1), aws = fp32 alpha(x2).
// Block tile: 2(z1) x 2(z2) x 64(z3); 256 threads = 4 waves.  [R3-proven config: lb(256,2)]
__global__ __launch_bounds__(256, 2) void nca_main(
    const float* __restrict__ xg, const float* __restrict__ w0g,
    const float* __restrict__ b0g, const float* __restrict__ w1g,
    const float* __restrict__ stg, float* __restrict__ outg,
    float* __restrict__ aws, unsigned char* __restrict__ plife)
{
  __shared__ u16t xs[8704];          // [4][4][34][16] bf16 x halo (2 z3 passes); reused as h buffers
  __shared__ u16t ys[16384];         // [8 kchunks][256 voxels][8] bf16 y, MFMA-A-friendly
  __shared__ float st_l[256];        // stoch fp32
  __shared__ float alpha_l[256];     // fp32 alpha(x2), staged for coalesced aws flush
  __shared__ unsigned char pl_l[256];// pre_life bits, staged for coalesced plife flush

  const int t = threadIdx.x;
  const int bid = blockIdx.x;
  const int b = bid >> 10;
  const int z1base = ((bid >> 5) & 31) * 2;
  const int z2base = (bid & 31) * 2;

  {
    int z1 = t >> 7, z2 = (t >> 6) & 1, z3 = t & 63;
    int gv = ((b * 64 + z1base + z1) * 64 + (z2base + z2)) * 64 + z3;
    st_l[t] = stg[gv];
  }

  for (int p = 0; p < 2; ++p) {
    if (p) __syncthreads();  // xs WAR vs previous pass conv reads
    // stage x halo (fp32 -> bf16): 544 rows x 16 ch = 2176 float4 chunks
    for (int it = 0; it < 9; ++it) {
      int q = t + it * 256;
      if (q < 2176) {
        int c4 = (q & 3) * 4, s = q >> 2;
        int i3 = s % 34, r = s / 34;
        int i2 = r & 3, i1 = r >> 2;
        int z1g = z1base + i1 - 1, z2g = z2base + i2 - 1, z3g = p * 32 + i3 - 1;
        f32x4 val = {0.f, 0.f, 0.f, 0.f};
        if ((unsigned)z1g < 64u && (unsigned)z2g < 64u && (unsigned)z3g < 64u) {
          int gv = ((b * 64 + z1g) * 64 + z2g) * 64 + z3g;
          val = *(const f32x4*)(xg + gv * 16 + c4);
        }
        ushort4v bv;
        #pragma unroll
        for (int j = 0; j < 4; ++j) bv[j] = f2bf(val[j]);
        *(ushort4v*)(xs + s * 16 + c4) = bv;
      }
    }
    __syncthreads();
    // conv: one (voxel, channel-half) per thread
    {
      const int hc = t & 1, v128 = t >> 1;
      const int z1 = v128 >> 6, z2 = (v128 >> 5) & 1, z3l = v128 & 31;
      const int v = z1 * 128 + z2 * 64 + p * 32 + z3l;
      float ax[8], ay[8], az[8];
      #pragma unroll
      for (int c = 0; c < 8; ++c) { ax[c] = 0.f; ay[c] = 0.f; az[c] = 0.f; }
      ushort8 ctr{};
      float amax = 0.0f;  // alpha>=0; 0-pad gives same >0.1 verdict as -inf pad
      const float W[3] = {1.f, 2.f, 1.f};
      const float D[3] = {-1.f, 0.f, 1.f};
      #pragma unroll
      for (int d1 = 0; d1 < 3; ++d1)
        #pragma unroll
        for (int d2 = 0; d2 < 3; ++d2)
          #pragma unroll
          for (int d3 = 0; d3 < 3; ++d3) {
            const int base = (((z1 + d1) * 4 + (z2 + d2)) * 34 + (z3l + d3)) * 16 + hc * 8;
            ushort8 u = *(const ushort8*)(xs + base);
            float f[8];
            #pragma unroll
            for (int c = 0; c < 8; ++c) f[c] = bf2f((u16t)u[c]);
            const float cx = W[d1] * W[d2] * D[d3] * 0.03125f;  // kx[k,i,j]=w[k]w[i]d[j]/32
            const float cy = W[d1] * D[d2] * W[d3] * 0.03125f;  // ky=kx.T(0,2,1)
            const float cz = D[d1] * W[d2] * W[d3] * 0.03125f;  // kz=kx.T(2,1,0)
            if (cx != 0.f) {
              #pragma unroll
              for (int c = 0; c < 8; ++c) ax[c] = fmaf(f[c], cx, ax[c]);
            }
            if (cy != 0.f) {
              #pragma unroll
              for (int c = 0; c < 8; ++c) ay[c] = fmaf(f[c], cy, ay[c]);
            }
            if (cz != 0.f) {
              #pragma unroll
              for (int c = 0; c < 8; ++c) az[c] = fmaf(f[c], cz, az[c]);
            }
            if (d1 == 1 && d2 == 1 && d3 == 1) ctr = u;
            amax = fmaxf(amax, f[3]);  // alpha = ch3 (meaningful for hc==0)
          }
      *(ushort8*)(ys + (0 + hc) * 2048 + v * 8) = ctr;
      ushort8 bx, by, bz;
      #pragma unroll
      for (int c = 0; c < 8; ++c) {
        bx[c] = (short)f2bf(ax[c]); by[c] = (short)f2bf(ay[c]); bz[c] = (short)f2bf(az[c]);
      }
      *(ushort8*)(ys + (2 + hc) * 2048 + v * 8) = bx;
      *(ushort8*)(ys + (4 + hc) * 2048 + v * 8) = by;
      *(ushort8*)(ys + (6 + hc) * 2048 + v * 8) = bz;
      if (hc == 0) pl_l[v] = (amax > 0.1f) ? (unsigned char)1 : (unsigned char)0;
    }
  }
  __syncthreads();

  // GEMM phase: per wave M=64 (4 m-tiles of 16); fc0 K=64 N=128; fc1 K=128 N=16
  {
    const int lane = t & 63, w = t >> 6;
    const int col = lane & 15, quad = lane >> 4;
    short8 w0f[2][8];  // B[k=kt*32+quad*8+j][n=nt*16+col] = w0[n][k], cvt fp32->bf16
    #pragma unroll
    for (int kt = 0; kt < 2; ++kt)
      #pragma unroll
      for (int nt = 0; nt < 8; ++nt) {
        const float* p = w0g + (nt * 16 + col) * 64 + kt * 32 + quad * 8;
        f32x4 lo = *(const f32x4*)p, hi = *(const f32x4*)(p + 4);
        short8 fr;
        #pragma unroll
        for (int j = 0; j < 4; ++j) { fr[j] = (short)f2bf(lo[j]); fr[4 + j] = (short)f2bf(hi[j]); }
        w0f[kt][nt] = fr;
      }
    short8 w1f[4];     // B[k][n=col] = w1[col][k]
    #pragma unroll
    for (int kt = 0; kt < 4; ++kt) {
      const float* p = w1g + col * 128 + kt * 32 + quad * 8;
      f32x4 lo = *(const f32x4*)p, hi = *(const f32x4*)(p + 4);
      short8 fr;
      #pragma unroll
      for (int j = 0; j < 4; ++j) { fr[j] = (short)f2bf(lo[j]); fr[4 + j] = (short)f2bf(hi[j]); }
      w1f[kt] = fr;
    }
    float bias[8];
    #pragma unroll
    for (int nt = 0; nt < 8; ++nt) bias[nt] = b0g[nt * 16 + col];

    u16t* hw = xs + w * 2176;  // per-wave h buffer [16][136]

    for (int mt = 0; mt < 4; ++mt) {
      const int mbase = w * 64 + mt * 16;
      short8 aF[2];  // A[m=col][k=kt*32+quad*8+j] = y[mbase+col][k]
      #pragma unroll
      for (int kt = 0; kt < 2; ++kt)
        aF[kt] = *(const short8*)(ys + (kt * 4 + quad) * 2048 + (mbase + col) * 8);
      f32x4 acc[8];
      #pragma unroll
      for (int nt = 0; nt < 8; ++nt) {
        f32x4 tmp = {bias[nt], bias[nt], bias[nt], bias[nt]};
        acc[nt] = tmp;
      }
      #pragma unroll
      for (int kt = 0; kt < 2; ++kt)
        #pragma unroll
        for (int nt = 0; nt < 8; ++nt)
          acc[nt] = __builtin_amdgcn_mfma_f32_16x16x32_bf16(aF[kt], w0f[kt][nt], acc[nt], 0, 0, 0);
      // relu -> bf16 -> LDS (C layout -> A layout); h[m=quad*4+r][k=nt*16+col]
      #pragma unroll
      for (int nt = 0; nt < 8; ++nt)
        #pragma unroll
        for (int r = 0; r < 4; ++r)
          hw[(quad * 4 + r) * 136 + nt * 16 + col] = f2bf(fmaxf(acc[nt][r], 0.0f));
      __syncthreads();  // order LDS write -> vector read (R3-proven)
      f32x4 dxa = {0.f, 0.f, 0.f, 0.f};
      #pragma unroll
      for (int kt = 0; kt < 4; ++kt) {
        short8 ah = *(const short8*)(hw + col * 136 + kt * 32 + quad * 8);
        dxa = __builtin_amdgcn_mfma_f32_16x16x32_bf16(ah, w1f[kt], dxa, 0, 0, 0);
      }
      // epilogue: out[v][col] = x[v][col] + mask*dx ; v = mbase+quad*4+r (xg re-read is L3-hot)
      #pragma unroll
      for (int r = 0; r < 4; ++r) {
        const int v = mbase + quad * 4 + r;
        const int gv = ((b * 64 + z1base + (v >> 7)) * 64 + (z2base + ((v >> 6) & 1))) * 64 + (v & 63);
        const int addr = gv * 16 + col;
        float dx = (st_l[v] > 0.5f) ? dxa[r] : 0.0f;
        float x2 = xg[addr] + dx;
        outg[addr] = x2;
        if (col == 3) alpha_l[v] = x2;  // stage fp32 alpha(x2) in LDS
      }
    }
  }
  __syncthreads();
  // coalesced aux flush: per wave 64 consecutive gv -> full-line writes only
  if (aws != nullptr) {
    const int v = t;
    const int gv = ((b * 64 + z1base + (v >> 7)) * 64 + (z2base + ((v >> 6) & 1))) * 64 + (v & 63);
    aws[gv] = alpha_l[v];
    plife[gv] = pl_l[v];
  }
}

// Kernel 2 (compact): life = plife & (maxpool3(aws) > 0.1); zero dead voxels in out.
__global__ void nca_life(const float* __restrict__ aws,
                         const unsigned char* __restrict__ plife,
                         float* __restrict__ og)
{
  __shared__ float a2[1056];  // [4][4][66] alpha(x2)
  const int t = threadIdx.x, bid = blockIdx.x;
  const int b = bid >> 10;
  const int z1base = ((bid >> 5) & 31) * 2;
  const int z2base = (bid & 31) * 2;
  for (int it = 0; it < 5; ++it) {
    int q = t + it * 256;
    if (q < 1056) {
      int i3 = q % 66, r = q / 66;
      int i2 = r & 3, i1 = r >> 2;
      int z1g = z1base + i1 - 1, z2g = z2base + i2 - 1, z3g = i3 - 1;
      float vo = 0.f;  // 0 pad: 0 > 0.1 false, same verdict as -inf pad
      if ((unsigned)z1g < 64u && (unsigned)z2g < 64u && (unsigned)z3g < 64u)
        vo = aws[((b * 64 + z1g) * 64 + z2g) * 64 + z3g];
      a2[q] = vo;
    }
  }
  __syncthreads();
  const int z1 = t >> 7, z2 = (t >> 6) & 1, z3 = t & 63;
  float mo = -1e30f;
  #pragma unroll
  for (int d1 = 0; d1 < 3; ++d1)
    #pragma unroll
    for (int d2 = 0; d2 < 3; ++d2)
      #pragma unroll
      for (int d3 = 0; d3 < 3; ++d3)
        mo = fmaxf(mo, a2[((z1 + d1) * 4 + (z2 + d2)) * 66 + (z3 + d3)]);
  const int gv = ((b * 64 + z1base + z1) * 64 + (z2base + z2)) * 64 + z3;
  const bool life = (plife[gv] != 0) && (mo > 0.1f);
  if (!life) {
    f32x4 z = {0.f, 0.f, 0.f, 0.f};
    #pragma unroll
    for (int j = 0; j < 4; ++j) *(f32x4*)(og + gv * 16 + j * 4) = z;
  }
}

// Fallback (no workspace): recompute both alive masks from strided global reads.
__global__ void nca_life_strided(const float* __restrict__ xg, const float* __restrict__ outg,
                                 float* __restrict__ og)
{
  __shared__ float a2x[1056];
  __shared__ float a2o[1056];
  const int t = threadIdx.x, bid = blockIdx.x;
  const int b = bid >> 10;
  const int z1base = ((bid >> 5) & 31) * 2;
  const int z2base = (bid & 31) * 2;
  for (int it = 0; it < 5; ++it) {
    int q = t + it * 256;
    if (q < 1056) {
      int i3 = q % 66, r = q / 66;
      int i2 = r & 3, i1 = r >> 2;
      int z1g = z1base + i1 - 1, z2g = z2base + i2 - 1, z3g = i3 - 1;
      float vx = 0.f, vo = 0.f;
      if ((unsigned)z1g < 64u && (unsigned)z2g < 64u && (unsigned)z3g < 64u) {
        int gv = ((b * 64 + z1g) * 64 + z2g) * 64 + z3g;
        vx = xg[gv * 16 + 3];
        vo = outg[gv * 16 + 3];
      }
      a2x[q] = vx; a2o[q] = vo;
    }
  }
  __syncthreads();
  const int z1 = t >> 7, z2 = (t >> 6) & 1, z3 = t & 63;
  float mx = -1e30f, mo = -1e30f;
  #pragma unroll
  for (int d1 = 0; d1 < 3; ++d1)
    #pragma unroll
    for (int d2 = 0; d2 < 3; ++d2)
      #pragma unroll
      for (int d3 = 0; d3 < 3; ++d3) {
        const int idx = ((z1 + d1) * 4 + (z2 + d2)) * 66 + (z3 + d3);
        mx = fmaxf(mx, a2x[idx]);
        mo = fmaxf(mo, a2o[idx]);
      }
  const bool life = (mx > 0.1f) && (mo > 0.1f);
  if (!life) {
    const int gv = ((b * 64 + z1base + z1) * 64 + (z2base + z2)) * 64 + z3;
    f32x4 z = {0.f, 0.f, 0.f, 0.f};
    #pragma unroll
    for (int j = 0; j < 4; ++j) *(f32x4*)(og + gv * 16 + j * 4) = z;
  }
}

extern "C" void kernel_launch(void* const* d_in, const int* in_sizes, int n_in,
                              void* d_out, int out_size, void* d_ws, size_t ws_size,
                              hipStream_t stream) {
  (void)out_size;
  const void *px = nullptr, *pw0 = nullptr, *pb0 = nullptr, *pw1 = nullptr, *pst = nullptr;
  for (int i = 0; i < n_in; ++i) {
    switch (in_sizes[i]) {
      case 16777216: px  = d_in[i]; break;  // x  [4,64,64,64,16]
      case 8192:     pw0 = d_in[i]; break;  // w0 [128,64]
      case 128:      pb0 = d_in[i]; break;  // b0 [128]
      case 2048:     pw1 = d_in[i]; break;  // w1 [16,128]
      case 1048576:  pst = d_in[i]; break;  // stoch [4,64,64,64,1]
    }
  }
  if (!px || !pw0 || !pb0 || !pw1 || !pst) {
    px = d_in[0]; pw0 = d_in[1]; pb0 = d_in[2]; pw1 = d_in[3]; pst = d_in[4];
  }
  float* outg = (float*)d_out;
  const size_t need = (size_t)VTOT * 4 + (size_t)VTOT;  // fp32 alpha + byte plife
  const bool use_ws = (d_ws != nullptr) && (ws_size >= need);
  float* aws = use_ws ? (float*)d_ws : nullptr;
  unsigned char* plife = use_ws ? ((unsigned char*)d_ws + (size_t)VTOT * 4) : nullptr;

  nca_main<<<4096, 256, 0, stream>>>((const float*)px, (const float*)pw0, (const float*)pb0,
                                     (const float*)pw1, (const float*)pst, outg, aws, plife);
  if (use_ws)
    nca_life<<<4096, 256, 0, stream>>>(aws, plife, outg);
  else
    nca_life_strided<<<4096, 256, 0, stream>>>((const float*)px, outg, outg);
}